// Round 7
// baseline (626.964 us; speedup 1.0000x reference)
//
#include <hip/hip_runtime.h>
#include <hip/hip_bf16.h>

typedef unsigned int uint32;
typedef unsigned short ushort16;

// float -> bf16 round-to-nearest-even
static __device__ __forceinline__ ushort16 f2bf(float f) {
    uint32 u = __float_as_uint(f);
    u += 0x7fffu + ((u >> 16) & 1u);
    return (ushort16)(u >> 16);
}
// unpack packed bf16 pair
static __device__ __forceinline__ float blo(uint32 u) { return __uint_as_float(u << 16); }
static __device__ __forceinline__ float bhi(uint32 u) { return __uint_as_float(u & 0xffff0000u); }

// ============ CSR build: histogram -> scan -> fill ============

__global__ void k_hist(const int* __restrict__ dst, int* __restrict__ counts, int E) {
    int e = blockIdx.x * blockDim.x + threadIdx.x;
    int stride = gridDim.x * blockDim.x;
    for (; e < E; e += stride) atomicAdd(&counts[dst[e]], 1);
}

__global__ void k_dinv(const int* __restrict__ counts, float* __restrict__ dinv, int N) {
    int i = blockIdx.x * blockDim.x + threadIdx.x;
    if (i < N) dinv[i] = rsqrtf((float)(counts[i] + 1));   // +1 self loop
}

__global__ void k_scan1(const int* __restrict__ counts, int* __restrict__ rowptr,
                        int* __restrict__ bsum, int N) {
    __shared__ int tmp[256];
    int i = blockIdx.x * 256 + threadIdx.x;
    int v = (i < N) ? counts[i] : 0;
    tmp[threadIdx.x] = v;
    __syncthreads();
    for (int off = 1; off < 256; off <<= 1) {
        int t = (threadIdx.x >= off) ? tmp[threadIdx.x - off] : 0;
        __syncthreads();
        tmp[threadIdx.x] += t;
        __syncthreads();
    }
    if (i < N) rowptr[i] = tmp[threadIdx.x] - v;
    if (threadIdx.x == 255) bsum[blockIdx.x] = tmp[255];
}

__global__ void k_scan2(int* bsum, int nb) {
    __shared__ int tmp[512];
    int t = threadIdx.x;
    int v = (t < nb) ? bsum[t] : 0;
    tmp[t] = v;
    __syncthreads();
    for (int off = 1; off < 512; off <<= 1) {
        int u = (t >= off) ? tmp[t - off] : 0;
        __syncthreads();
        tmp[t] += u;
        __syncthreads();
    }
    if (t < nb) bsum[t] = tmp[t] - v;
}

__global__ void k_scan3(int* __restrict__ rowptr, int* __restrict__ cursor,
                        const int* __restrict__ bsum, int N) {
    int i = blockIdx.x * 256 + threadIdx.x;
    if (i < N) {
        int v = rowptr[i] + bsum[blockIdx.x];
        rowptr[i] = v;
        cursor[i] = v;
    }
}

// batched fill: 2 edges/thread, full thread-slot coverage, atomics pipelined
__global__ __launch_bounds__(256) void k_fill(const int* __restrict__ ei,
                                              int* __restrict__ cursor,
                                              int* __restrict__ ssrc, int E) {
    int t = blockIdx.x * 256 + threadIdx.x;
    int nt = gridDim.x * 256;
    int s[2], d[2], p[2];
#pragma unroll
    for (int i = 0; i < 2; ++i) {
        int e = t + i * nt;
        if (e < E) { s[i] = ei[e]; d[i] = ei[E + e]; }
    }
#pragma unroll
    for (int i = 0; i < 2; ++i) {
        int e = t + i * nt;
        if (e < E) p[i] = atomicAdd(&cursor[d[i]], 1);
    }
#pragma unroll
    for (int i = 0; i < 2; ++i) {
        int e = t + i * nt;
        if (e < E) ssrc[p[i]] = s[i];
    }
}

// ============ embed GEMM: h = x @ We^T ([N,128] @ [128,64]^T) ============

__global__ __launch_bounds__(256) void k_embed(const float* __restrict__ x,
                                               const float* __restrict__ We,
                                               float* __restrict__ h, int N) {
    __shared__ float Ws[64 * 129];
    __shared__ float xs[32 * 128];
    int tid = threadIdx.x;

#pragma unroll
    for (int i = 0; i < 32; ++i) {
        int m = tid + i * 256;
        Ws[(m >> 7) * 129 + (m & 127)] = We[m];
    }
    int base = blockIdx.x * 32;
    const float4* x4 = (const float4*)(x + (size_t)base * 128);
#pragma unroll
    for (int i = 0; i < 4; ++i) {
        int m = tid + i * 256;
        ((float4*)xs)[m] = x4[m];
    }
    __syncthreads();

    int f = tid & 63, g = tid >> 6;
    float acc[8] = {0, 0, 0, 0, 0, 0, 0, 0};
#pragma unroll 4
    for (int k = 0; k < 128; k += 4) {
        float w0 = Ws[f * 129 + k + 0];
        float w1 = Ws[f * 129 + k + 1];
        float w2 = Ws[f * 129 + k + 2];
        float w3 = Ws[f * 129 + k + 3];
#pragma unroll
        for (int j = 0; j < 8; ++j) {
            const float4 xv = *(const float4*)&xs[(g * 8 + j) * 128 + k];
            acc[j] = fmaf(xv.x, w0, acc[j]);
            acc[j] = fmaf(xv.y, w1, acc[j]);
            acc[j] = fmaf(xv.z, w2, acc[j]);
            acc[j] = fmaf(xv.w, w3, acc[j]);
        }
    }
#pragma unroll
    for (int j = 0; j < 8; ++j) {
        int r = base + g * 8 + j;
        h[(size_t)r * 64 + f] = acc[j];
    }
}

// ============ GCN layer GEMM: hws = bf16((act(hin) @ Wg^T) * dinv) ============

__global__ __launch_bounds__(256) void k_gcn(const float* __restrict__ hin,
                                             const float* __restrict__ Wg,
                                             const float* __restrict__ bias_prev, int act,
                                             const float* __restrict__ dinv,
                                             ushort16* __restrict__ hwsb, int N) {
    __shared__ float Ws[64 * 65];
    __shared__ float xs[32 * 64];
    int tid = threadIdx.x;

#pragma unroll
    for (int i = 0; i < 16; ++i) {
        int m = tid + i * 256;
        Ws[(m >> 6) * 65 + (m & 63)] = Wg[m];
    }
    int base = blockIdx.x * 32;
    const float4* hin4 = (const float4*)(hin + (size_t)base * 64);
#pragma unroll
    for (int i = 0; i < 2; ++i) {
        int m = tid + i * 256;
        float4 v = hin4[m];
        if (act) {
            int kf = (m & 15) * 4;
            v.x = fmaxf(v.x + bias_prev[kf + 0], 0.f);
            v.y = fmaxf(v.y + bias_prev[kf + 1], 0.f);
            v.z = fmaxf(v.z + bias_prev[kf + 2], 0.f);
            v.w = fmaxf(v.w + bias_prev[kf + 3], 0.f);
        }
        ((float4*)xs)[m] = v;
    }
    __syncthreads();

    int f = tid & 63, g = tid >> 6;
    float acc[8] = {0, 0, 0, 0, 0, 0, 0, 0};
#pragma unroll 4
    for (int k = 0; k < 64; k += 4) {
        float w0 = Ws[f * 65 + k + 0];
        float w1 = Ws[f * 65 + k + 1];
        float w2 = Ws[f * 65 + k + 2];
        float w3 = Ws[f * 65 + k + 3];
#pragma unroll
        for (int j = 0; j < 8; ++j) {
            const float4 xv = *(const float4*)&xs[(g * 8 + j) * 64 + k];
            acc[j] = fmaf(xv.x, w0, acc[j]);
            acc[j] = fmaf(xv.y, w1, acc[j]);
            acc[j] = fmaf(xv.z, w2, acc[j]);
            acc[j] = fmaf(xv.w, w3, acc[j]);
        }
    }
#pragma unroll
    for (int j = 0; j < 8; ++j) {
        int r = base + g * 8 + j;
        hwsb[(size_t)r * 64 + f] = f2bf(acc[j] * dinv[r]);
    }
}

// ============ CSR gather-aggregate: scalar index stream + uint2 gathers ============
// out[d] = dinv[d] * (hws[d] + sum_{e in row d} hws[src_e])
// lane = (sub, q): sub = lane>>4 picks 1 of 4 rows per load, q = lane&15 picks
// the uint2 (4 bf16 feats) within the 128-B row. Edge indices are read via
// wave-uniform scalar loads (s_load), eliminating the ds_bpermute chain.

__global__ __launch_bounds__(256) void k_agg(const int* __restrict__ rowptr,
                                             const int* __restrict__ counts,
                                             const int* __restrict__ ssrc,
                                             const float* __restrict__ dinv,
                                             const uint2* __restrict__ hws2,
                                             float* __restrict__ out, int N) {
    int lane = threadIdx.x & 63;
    int d = blockIdx.x * 4 + (threadIdx.x >> 6);
    if (d >= N) return;
    int q = lane & 15;
    int sub = lane >> 4;
    bool m0 = (sub == 0), m1 = (sub == 1), m2 = (sub == 2);

    float a0 = 0.f, a1 = 0.f, a2 = 0.f, a3 = 0.f;
    if (m0) {   // self loop counted once
        uint2 v = hws2[((size_t)d << 4) + q];
        a0 = blo(v.x); a1 = bhi(v.x); a2 = blo(v.y); a3 = bhi(v.y);
    }

    int beg = __builtin_amdgcn_readfirstlane(rowptr[d]);
    int cnt = __builtin_amdgcn_readfirstlane(counts[d]);
    const int* srow = ssrc + beg;

    int j = 0;
    for (; j + 16 <= cnt; j += 16) {
        int e0 = srow[j + 0],  e1 = srow[j + 1],  e2 = srow[j + 2],  e3 = srow[j + 3];
        int e4 = srow[j + 4],  e5 = srow[j + 5],  e6 = srow[j + 6],  e7 = srow[j + 7];
        int e8 = srow[j + 8],  e9 = srow[j + 9],  e10 = srow[j + 10], e11 = srow[j + 11];
        int e12 = srow[j + 12], e13 = srow[j + 13], e14 = srow[j + 14], e15 = srow[j + 15];
        int t0 = m0 ? e0  : (m1 ? e1  : (m2 ? e2  : e3));
        int t1 = m0 ? e4  : (m1 ? e5  : (m2 ? e6  : e7));
        int t2 = m0 ? e8  : (m1 ? e9  : (m2 ? e10 : e11));
        int t3 = m0 ? e12 : (m1 ? e13 : (m2 ? e14 : e15));
        uint2 v0 = hws2[((size_t)t0 << 4) + q];
        uint2 v1 = hws2[((size_t)t1 << 4) + q];
        uint2 v2 = hws2[((size_t)t2 << 4) + q];
        uint2 v3 = hws2[((size_t)t3 << 4) + q];
        a0 += blo(v0.x) + blo(v1.x) + blo(v2.x) + blo(v3.x);
        a1 += bhi(v0.x) + bhi(v1.x) + bhi(v2.x) + bhi(v3.x);
        a2 += blo(v0.y) + blo(v1.y) + blo(v2.y) + blo(v3.y);
        a3 += bhi(v0.y) + bhi(v1.y) + bhi(v2.y) + bhi(v3.y);
    }
    if (j + 8 <= cnt) {
        int e0 = srow[j + 0], e1 = srow[j + 1], e2 = srow[j + 2], e3 = srow[j + 3];
        int e4 = srow[j + 4], e5 = srow[j + 5], e6 = srow[j + 6], e7 = srow[j + 7];
        int t0 = m0 ? e0 : (m1 ? e1 : (m2 ? e2 : e3));
        int t1 = m0 ? e4 : (m1 ? e5 : (m2 ? e6 : e7));
        uint2 v0 = hws2[((size_t)t0 << 4) + q];
        uint2 v1 = hws2[((size_t)t1 << 4) + q];
        a0 += blo(v0.x) + blo(v1.x);
        a1 += bhi(v0.x) + bhi(v1.x);
        a2 += blo(v0.y) + blo(v1.y);
        a3 += bhi(v0.y) + bhi(v1.y);
        j += 8;
    }
    if (j + 4 <= cnt) {
        int e0 = srow[j + 0], e1 = srow[j + 1], e2 = srow[j + 2], e3 = srow[j + 3];
        int t0 = m0 ? e0 : (m1 ? e1 : (m2 ? e2 : e3));
        uint2 v0 = hws2[((size_t)t0 << 4) + q];
        a0 += blo(v0.x); a1 += bhi(v0.x); a2 += blo(v0.y); a3 += bhi(v0.y);
        j += 4;
    }
    for (; j < cnt; ++j) {
        int ej = srow[j];
        if (m0) {
            uint2 v = hws2[((size_t)ej << 4) + q];
            a0 += blo(v.x); a1 += bhi(v.x); a2 += blo(v.y); a3 += bhi(v.y);
        }
    }

    // combine across the 4 subs (lanes 16 apart hold the same q)
    a0 += __shfl_xor(a0, 16); a1 += __shfl_xor(a1, 16);
    a2 += __shfl_xor(a2, 16); a3 += __shfl_xor(a3, 16);
    a0 += __shfl_xor(a0, 32); a1 += __shfl_xor(a1, 32);
    a2 += __shfl_xor(a2, 32); a3 += __shfl_xor(a3, 32);

    if (m0) {
        float dd = dinv[d];
        ((float4*)out)[((size_t)d << 4) + q] =
            make_float4(dd * a0, dd * a1, dd * a2, dd * a3);
    }
}

// ============ centroid squared norms ============

__global__ void k_c2(const float* __restrict__ C, float* __restrict__ c2) {
    int k = threadIdx.x;
    if (k < 100) {
        float s = 0.f;
        for (int d = 0; d < 64; ++d) { float v = C[k * 64 + d]; s = fmaf(v, v, s); }
        c2[k] = s;
    }
}

// ============ centroid distances + pooling: thread = node, quadratic form ============

__global__ __launch_bounds__(256) void k_cent(const float* __restrict__ hin,
                                              const float* __restrict__ b2,
                                              const float* __restrict__ C,
                                              const float* __restrict__ c2g,
                                              float* __restrict__ pooled, int N) {
    __shared__ float pooled_s[128];
    int tid = threadIdx.x;
    if (tid < 128) pooled_s[tid] = 0.f;
    __syncthreads();

    int n = blockIdx.x * 256 + tid;
    bool valid = n < N;

    float h[64];
    float h2 = 0.f;
    {
        const float4* h4 = (const float4*)(hin + ((size_t)(valid ? n : 0) << 6));
#pragma unroll
        for (int i = 0; i < 16; ++i) {
            float4 v = h4[i];
            v.x = fmaxf(v.x + b2[4 * i + 0], 0.f);
            v.y = fmaxf(v.y + b2[4 * i + 1], 0.f);
            v.z = fmaxf(v.z + b2[4 * i + 2], 0.f);
            v.w = fmaxf(v.w + b2[4 * i + 3], 0.f);
            h[4 * i + 0] = v.x; h[4 * i + 1] = v.y;
            h[4 * i + 2] = v.z; h[4 * i + 3] = v.w;
            h2 = fmaf(v.x, v.x, h2); h2 = fmaf(v.y, v.y, h2);
            h2 = fmaf(v.z, v.z, h2); h2 = fmaf(v.w, v.w, h2);
        }
    }

    for (int k = 0; k < 100; ++k) {
        const float* crow = C + k * 64;
        float acc = 0.f;
#pragma unroll
        for (int d = 0; d < 64; ++d) acc = fmaf(h[d], crow[d], acc);
        float d2 = fmaxf(h2 + c2g[k] - 2.f * acc, 0.f);
        float dist = valid ? sqrtf(d2 + 1e-12f) : 0.f;
#pragma unroll
        for (int off = 32; off > 0; off >>= 1) dist += __shfl_xor(dist, off);
        if ((tid & 63) == 0) atomicAdd(&pooled_s[k], dist);
    }
    __syncthreads();
    if (tid < 100) atomicAdd(&pooled[tid], pooled_s[tid]);
}

// ============ output head ============

__global__ void k_out(const float* __restrict__ pooled,
                      const float* __restrict__ Wout,
                      const float* __restrict__ bout,
                      float* __restrict__ out, float invN) {
    int t = threadIdx.x;
    if (t < 10) {
        float s = 0.f;
        for (int k = 0; k < 100; ++k) s += pooled[k] * Wout[t * 100 + k];
        out[t] = s * invN + bout[t];
    }
}

// ============ launcher ============

extern "C" void kernel_launch(void* const* d_in, const int* in_sizes, int n_in,
                              void* d_out, int out_size, void* d_ws, size_t ws_size,
                              hipStream_t stream) {
    const float* x    = (const float*)d_in[0];
    const int*   ei   = (const int*)d_in[1];
    const float* We   = (const float*)d_in[2];
    const float* Wg   = (const float*)d_in[3];
    const float* bg   = (const float*)d_in[4];
    const float* C    = (const float*)d_in[5];
    const float* Wout = (const float*)d_in[6];
    const float* bout = (const float*)d_in[7];
    float*       out  = (float*)d_out;

    const int N = in_sizes[0] / 128;    // 100000
    const int E = in_sizes[1] / 2;      // 1600000
    const int NB = (N + 255) / 256;     // scan blocks (391)

    char* ws = (char*)d_ws;
    size_t off = 0;
    auto alloc = [&](size_t bytes) { void* p = ws + off; off += (bytes + 511) & ~(size_t)511; return p; };
    float*    dinv   = (float*)alloc((size_t)N * 4);
    int*      counts = (int*)  alloc((size_t)N * 4);
    int*      cursor = (int*)  alloc((size_t)N * 4);
    int*      rowptr = (int*)  alloc((size_t)N * 4);
    int*      bsum   = (int*)  alloc((size_t)NB * 4);
    int*      ssrc   = (int*)  alloc((size_t)E * 4);
    float*    hA     = (float*)alloc((size_t)N * 64 * 4);
    ushort16* hB     = (ushort16*)alloc((size_t)N * 64 * 2);   // bf16 hws
    float*    c2     = (float*)alloc(512);
    float*    pooled = (float*)alloc(512);

    hipMemsetAsync(counts, 0, (size_t)N * 4, stream);
    hipMemsetAsync(pooled, 0, 512, stream);

    // CSR build
    k_hist<<<4096, 256, 0, stream>>>(ei + E, counts, E);
    k_dinv<<<NB, 256, 0, stream>>>(counts, dinv, N);
    k_scan1<<<NB, 256, 0, stream>>>(counts, rowptr, bsum, N);
    k_scan2<<<1, 512, 0, stream>>>(bsum, NB);
    k_scan3<<<NB, 256, 0, stream>>>(rowptr, cursor, bsum, N);
    k_fill<<<(E + 511) / 512, 256, 0, stream>>>(ei, cursor, ssrc, E);
    k_c2<<<1, 128, 0, stream>>>(C, c2);

    // embed
    k_embed<<<N / 32, 256, 0, stream>>>(x, We, hA, N);

    // 3 GCN layers: gemm (hA -> hB bf16, scaled by dinv), aggregate (hB -> hA fp32)
    for (int l = 0; l < 3; ++l) {
        const float* bias_prev = (l == 0) ? bg : (bg + (l - 1) * 64);
        int act = (l == 0) ? 0 : 1;
        k_gcn<<<N / 32, 256, 0, stream>>>(hA, Wg + (size_t)l * 64 * 64, bias_prev, act,
                                          dinv, hB, N);
        k_agg<<<(N + 3) / 4, 256, 0, stream>>>(rowptr, counts, ssrc, dinv,
                                               (const uint2*)hB, hA, N);
    }

    // centroid distances + pooling (applies relu + b_gcn[2])
    k_cent<<<NB, 256, 0, stream>>>(hA, bg + 2 * 64, C, c2, pooled, N);

    // head
    k_out<<<1, 64, 0, stream>>>(pooled, Wout, bout, out, 1.0f / (float)N);
}